// Round 1
// baseline (514.878 us; speedup 1.0000x reference)
//
#include <hip/hip_runtime.h>
#include <hip/hip_bf16.h>

// GAT layer, N=8192, DIN=256, DOUT=128.
// Math: h = x@W+bW; e_ij = leaky_relu(s_src[i]+s_dst[j]+ba); p = adj ? exp(e) : 0
// (no max-subtraction needed: |e| <= ~8 unmasked, fp32-safe). out_i = (sum_j p_ij h_j) / (sum_j p_ij).
// Structure: prep WT(bf16,transposed) -> MFMA h-GEMM (+fused s_src/s_dst, hbT bf16 transposed)
//            -> masked-softmax MFMA attention (j-split x2 partials) -> combine/divide.

#define NN 8192
#define DIN 256
#define DOUT 128

typedef __attribute__((ext_vector_type(8))) short short8;   // 8 bf16 = 4 VGPRs (MFMA A/B frag)
typedef __attribute__((ext_vector_type(4))) float floatx4;  // MFMA C/D frag

// ---------------- kernel 0: W [256][128] fp32 -> WT [128][256] bf16 ----------------
__global__ void prep_wt(const float* __restrict__ W, __hip_bfloat16* __restrict__ WT) {
    int e = blockIdx.x * blockDim.x + threadIdx.x;
    if (e < DIN * DOUT) {
        int k = e >> 7;        // 0..255
        int d = e & 127;       // 0..127
        WT[d * DIN + k] = __float2bfloat16(W[e]);
    }
}

// ---------------- kernel 1: h = x@W + bW (MFMA), fused s_src/s_dst, store hbT ----------------
// grid 256 blocks x 256 threads. Block handles 32 rows. Wave w: rows (w>>1)*16, cols (w&1)*64.
__global__ __launch_bounds__(256, 4) void gat_h(
    const float* __restrict__ x, const __hip_bfloat16* __restrict__ WT,
    const float* __restrict__ bW, const float* __restrict__ a1, const float* __restrict__ a2,
    __hip_bfloat16* __restrict__ hbT, float* __restrict__ s_src, float* __restrict__ s_dst) {
    int tid = threadIdx.x;
    int w = tid >> 6, lane = tid & 63;
    int lm = lane & 15, lq = lane >> 4;
    int i0 = blockIdx.x * 32;
    int r0 = (w >> 1) * 16;
    int c0 = (w & 1) * 64;

    __shared__ float s1s[32], s2s[32];
    if (tid < 32) { s1s[tid] = 0.f; s2s[tid] = 0.f; }
    __syncthreads();

    floatx4 acc[4] = {};
#pragma unroll
    for (int kk = 0; kk < DIN; kk += 32) {
        // A-frag: x[i0+r0+lm][kk + lq*8 + 0..7], fp32 -> bf16
        const float4* xp = (const float4*)&x[(size_t)(i0 + r0 + lm) * DIN + kk + lq * 8];
        float4 xa = xp[0], xb = xp[1];
        union { short8 v; __hip_bfloat16 h[8]; } af;
        af.h[0] = __float2bfloat16(xa.x); af.h[1] = __float2bfloat16(xa.y);
        af.h[2] = __float2bfloat16(xa.z); af.h[3] = __float2bfloat16(xa.w);
        af.h[4] = __float2bfloat16(xb.x); af.h[5] = __float2bfloat16(xb.y);
        af.h[6] = __float2bfloat16(xb.z); af.h[7] = __float2bfloat16(xb.w);
#pragma unroll
        for (int t = 0; t < 4; t++) {
            int d = c0 + 16 * t + lm;
            short8 bf = *(const short8*)&WT[(size_t)d * DIN + kk + lq * 8];
            acc[t] = __builtin_amdgcn_mfma_f32_16x16x32_bf16(af.v, bf, acc[t], 0, 0, 0);
        }
    }
    // epilogue: C/D layout col=lane&15, row=lq*4+r
    float s1[4] = {0.f, 0.f, 0.f, 0.f}, s2[4] = {0.f, 0.f, 0.f, 0.f};
#pragma unroll
    for (int t = 0; t < 4; t++) {
        int d = c0 + 16 * t + lm;
        float A1 = a1[d], A2 = a2[d], B = bW[d];
#pragma unroll
        for (int r = 0; r < 4; r++) {
            int row = r0 + lq * 4 + r;
            float h = acc[t][r] + B;
            hbT[(size_t)d * NN + i0 + row] = __float2bfloat16(h);
            s1[r] += h * A1;
            s2[r] += h * A2;
        }
    }
#pragma unroll
    for (int r = 0; r < 4; r++) {
        for (int m = 1; m < 16; m <<= 1) {
            s1[r] += __shfl_xor(s1[r], m, 64);
            s2[r] += __shfl_xor(s2[r], m, 64);
        }
    }
    if (lm == 0) {
#pragma unroll
        for (int r = 0; r < 4; r++) {
            int row = r0 + lq * 4 + r;
            atomicAdd(&s1s[row], s1[r]);
            atomicAdd(&s2s[row], s2[r]);
        }
    }
    __syncthreads();
    if (tid < 32) {
        s_src[i0 + tid] = s1s[tid];
        s_dst[i0 + tid] = s2s[tid];
    }
}

// ---------------- kernel 2: masked softmax-weighted GEMM (flash-style, no rescale) ----------------
// grid 1024 = 512 row-blocks (16 rows each) x 2 j-halves. 256 threads = 4 waves.
// Wave w covers cols [32w, 32w+32). Per j-tile of 32: compute p (bf16) into LDS, MFMA P@Hb.
__global__ __launch_bounds__(256, 4) void gat_attn(
    const int* __restrict__ adj, const float* __restrict__ s_src,
    const float* __restrict__ s_dst, const float* __restrict__ ba_p,
    const __hip_bfloat16* __restrict__ hbT,
    float* __restrict__ num, float* __restrict__ lpart) {
    int tid = threadIdx.x;
    int b = blockIdx.x;
    int ib = b & 511;
    int jh = b >> 9;
    int i0 = ib * 16;
    size_t jbase = (size_t)jh * 4096;

    __shared__ float ss[16];
    __shared__ __hip_bfloat16 pb[2][16][32];

    if (tid < 16) ss[tid] = s_src[i0 + tid];
    float ba = ba_p[0];
    __syncthreads();

    int w = tid >> 6, lane = tid & 63;
    int lm = lane & 15, lq = lane >> 4;
    int pi = tid >> 4;        // p-row 0..15
    int pj = (tid & 15) * 2;  // p-col pair

    floatx4 acc0 = {}, acc1 = {};
    float lsum = 0.f;
    float ssi = ss[pi] + ba;

    const int* adjrow = adj + (size_t)(i0 + pi) * NN + jbase + pj;
    const float* sdrow = s_dst + jbase + pj;
    const __hip_bfloat16* hb0p = hbT + (size_t)(w * 32 + lm) * NN + jbase + lq * 8;
    const __hip_bfloat16* hb1p = hb0p + (size_t)16 * NN;

    // prefetch tile 0
    int2 adjn = *(const int2*)adjrow;
    float2 sdn = *(const float2*)sdrow;
    short8 hb0n = *(const short8*)hb0p;
    short8 hb1n = *(const short8*)hb1p;

    for (int t = 0; t < 128; t++) {
        int2 adjc = adjn;
        float2 sdc = sdn;
        short8 hb0 = hb0n, hb1 = hb1n;
        if (t < 127) {
            adjn = *(const int2*)(adjrow + (t + 1) * 32);
            sdn = *(const float2*)(sdrow + (t + 1) * 32);
            hb0n = *(const short8*)(hb0p + (t + 1) * 32);
            hb1n = *(const short8*)(hb1p + (t + 1) * 32);
        }
        float e0 = ssi + sdc.x; e0 = e0 > 0.f ? e0 : 0.01f * e0;
        float e1 = ssi + sdc.y; e1 = e1 > 0.f ? e1 : 0.01f * e1;
        float p0 = adjc.x ? __expf(e0) : 0.f;
        float p1 = adjc.y ? __expf(e1) : 0.f;
        __hip_bfloat16 q0 = __float2bfloat16(p0), q1 = __float2bfloat16(p1);
        lsum += __bfloat162float(q0) + __bfloat162float(q1);  // denom matches bf16 numerator weights
        int buf = t & 1;
        pb[buf][pi][pj] = q0;
        pb[buf][pi][pj + 1] = q1;
        __syncthreads();
        short8 af = *(const short8*)&pb[buf][lm][lq * 8];
        acc0 = __builtin_amdgcn_mfma_f32_16x16x32_bf16(af, hb0, acc0, 0, 0, 0);
        acc1 = __builtin_amdgcn_mfma_f32_16x16x32_bf16(af, hb1, acc1, 0, 0, 0);
        // no second barrier: next iter writes the other pb buffer; the barrier above
        // orders (write t+2 of buf) after (everyone's ds_read of buf at t completed).
    }
    // denominator partial: reduce over the 16 threads sharing pi (lane bits 0..3)
    for (int m = 1; m < 16; m <<= 1) lsum += __shfl_xor(lsum, m, 64);
    if ((tid & 15) == 0) lpart[(size_t)jh * NN + i0 + pi] = lsum;

    float* nb = num + (size_t)jh * NN * DOUT;
#pragma unroll
    for (int r = 0; r < 4; r++) {
        int row = i0 + lq * 4 + r;
        nb[(size_t)row * DOUT + w * 32 + lm] = acc0[r];
        nb[(size_t)row * DOUT + w * 32 + 16 + lm] = acc1[r];
    }
}

// ---------------- kernel 3: combine partials, divide ----------------
__global__ void gat_combine(const float* __restrict__ num, const float* __restrict__ lpart,
                            float* __restrict__ out) {
    int gid = blockIdx.x * blockDim.x + threadIdx.x;  // 262144 threads
    int idx = gid * 4;
    int i = idx >> 7;
    float inv = 1.0f / (lpart[i] + lpart[NN + i]);
    float4 n0 = *(const float4*)&num[idx];
    float4 n1 = *(const float4*)&num[(size_t)NN * DOUT + idx];
    float4 o;
    o.x = (n0.x + n1.x) * inv;
    o.y = (n0.y + n1.y) * inv;
    o.z = (n0.z + n1.z) * inv;
    o.w = (n0.w + n1.w) * inv;
    *(float4*)&out[idx] = o;
}

extern "C" void kernel_launch(void* const* d_in, const int* in_sizes, int n_in,
                              void* d_out, int out_size, void* d_ws, size_t ws_size,
                              hipStream_t stream) {
    const float* x  = (const float*)d_in[0];
    const int* adj  = (const int*)d_in[1];
    const float* W  = (const float*)d_in[2];
    const float* bW = (const float*)d_in[3];
    const float* a1 = (const float*)d_in[4];
    const float* a2 = (const float*)d_in[5];
    const float* ba = (const float*)d_in[6];
    float* out = (float*)d_out;

    char* ws = (char*)d_ws;
    __hip_bfloat16* hbT = (__hip_bfloat16*)ws;                    // 2 MB   [128][8192]
    __hip_bfloat16* WT  = (__hip_bfloat16*)(ws + 2097152);        // 64 KB  [128][256]
    float* s_src        = (float*)(ws + 2162688);                 // 32 KB
    float* s_dst        = (float*)(ws + 2195456);                 // 32 KB
    float* num          = (float*)(ws + 2228224);                 // 8 MB   [2][8192][128]
    float* lpart        = (float*)(ws + 10616832);                // 64 KB  [2][8192]
    // total ws use: ~10.2 MB; all regions fully written before read each launch.

    prep_wt<<<128, 256, 0, stream>>>(W, WT);
    gat_h<<<256, 256, 0, stream>>>(x, WT, bW, a1, a2, hbT, s_src, s_dst);
    gat_attn<<<1024, 256, 0, stream>>>(adj, s_src, s_dst, ba, hbT, num, lpart);
    gat_combine<<<1024, 256, 0, stream>>>(num, lpart, out);
}

// Round 2
// 512.340 us; speedup vs baseline: 1.0050x; 1.0050x over previous
//
#include <hip/hip_runtime.h>
#include <hip/hip_bf16.h>

// GAT layer, N=8192, DIN=256, DOUT=128.
// h = x@W+bW; e_ij = leaky_relu(s_src[i]+s_dst[j]+ba); p = adj ? exp(e) : 0
// (no max-subtraction: |e| <= ~10 unmasked, fp32-safe). out_i = (sum_j p_ij h_j)/(sum_j p_ij).
//
// R2 redesign of gat_attn: no LDS, no barriers. p is computed straight into the
// MFMA A-fragment layout (lane(lm,lq) holds A[m=lm][k=lq*8+j], j=0..7 -> 8
// consecutive adj ints = 2x int4 per lane). Each wave: 16 rows x 128 dims via
// 8 B-frags from hbT (bf16, transposed) + a 9th MFMA vs constant-ones B-frag
// that yields the denominator (rowsum of the *bf16-rounded* p - exactly the
// weights the numerator uses). Grid = 128 row-blocks x jsplit partials.

#define NN 8192
#define DIN 256
#define DOUT 128

typedef __attribute__((ext_vector_type(8))) short short8;   // 8 bf16 = 4 VGPRs (MFMA A/B frag)
typedef __attribute__((ext_vector_type(4))) float floatx4;  // MFMA C/D frag

// ---------------- kernel 0: W [256][128] fp32 -> WT [128][256] bf16 ----------------
__global__ void prep_wt(const float* __restrict__ W, __hip_bfloat16* __restrict__ WT) {
    int e = blockIdx.x * blockDim.x + threadIdx.x;
    if (e < DIN * DOUT) {
        int k = e >> 7;        // 0..255
        int d = e & 127;       // 0..127
        WT[d * DIN + k] = __float2bfloat16(W[e]);
    }
}

// ---------------- kernel 1: h = x@W + bW (MFMA), fused s_src/s_dst, store hbT ----------------
// grid 256 blocks x 256 threads. Block handles 32 rows. Wave w: rows (w>>1)*16, cols (w&1)*64.
__global__ __launch_bounds__(256, 4) void gat_h(
    const float* __restrict__ x, const __hip_bfloat16* __restrict__ WT,
    const float* __restrict__ bW, const float* __restrict__ a1, const float* __restrict__ a2,
    __hip_bfloat16* __restrict__ hbT, float* __restrict__ s_src, float* __restrict__ s_dst) {
    int tid = threadIdx.x;
    int w = tid >> 6, lane = tid & 63;
    int lm = lane & 15, lq = lane >> 4;
    int i0 = blockIdx.x * 32;
    int r0 = (w >> 1) * 16;
    int c0 = (w & 1) * 64;

    __shared__ float s1s[32], s2s[32];
    if (tid < 32) { s1s[tid] = 0.f; s2s[tid] = 0.f; }
    __syncthreads();

    floatx4 acc[4] = {};
#pragma unroll
    for (int kk = 0; kk < DIN; kk += 32) {
        const float4* xp = (const float4*)&x[(size_t)(i0 + r0 + lm) * DIN + kk + lq * 8];
        float4 xa = xp[0], xb = xp[1];
        union { short8 v; __hip_bfloat16 h[8]; } af;
        af.h[0] = __float2bfloat16(xa.x); af.h[1] = __float2bfloat16(xa.y);
        af.h[2] = __float2bfloat16(xa.z); af.h[3] = __float2bfloat16(xa.w);
        af.h[4] = __float2bfloat16(xb.x); af.h[5] = __float2bfloat16(xb.y);
        af.h[6] = __float2bfloat16(xb.z); af.h[7] = __float2bfloat16(xb.w);
#pragma unroll
        for (int t = 0; t < 4; t++) {
            int d = c0 + 16 * t + lm;
            short8 bf = *(const short8*)&WT[(size_t)d * DIN + kk + lq * 8];
            acc[t] = __builtin_amdgcn_mfma_f32_16x16x32_bf16(af.v, bf, acc[t], 0, 0, 0);
        }
    }
    float s1[4] = {0.f, 0.f, 0.f, 0.f}, s2[4] = {0.f, 0.f, 0.f, 0.f};
#pragma unroll
    for (int t = 0; t < 4; t++) {
        int d = c0 + 16 * t + lm;
        float A1 = a1[d], A2 = a2[d], B = bW[d];
#pragma unroll
        for (int r = 0; r < 4; r++) {
            int row = r0 + lq * 4 + r;
            float h = acc[t][r] + B;
            hbT[(size_t)d * NN + i0 + row] = __float2bfloat16(h);
            s1[r] += h * A1;
            s2[r] += h * A2;
        }
    }
#pragma unroll
    for (int r = 0; r < 4; r++) {
        for (int m = 1; m < 16; m <<= 1) {
            s1[r] += __shfl_xor(s1[r], m, 64);
            s2[r] += __shfl_xor(s2[r], m, 64);
        }
    }
    if (lm == 0) {
#pragma unroll
        for (int r = 0; r < 4; r++) {
            int row = r0 + lq * 4 + r;
            atomicAdd(&s1s[row], s1[r]);
            atomicAdd(&s2s[row], s2[r]);
        }
    }
    __syncthreads();
    if (tid < 32) {
        s_src[i0 + tid] = s1s[tid];
        s_dst[i0 + tid] = s2s[tid];
    }
}

// ---------------- kernel 2: masked softmax-weighted GEMM, barrier-free ----------------
// grid = 128 row-blocks x jsplit. 256 threads = 4 waves; wave w owns rows
// ib*64 + w*16 .. +15 and ALL 128 output dims. njt = j-tiles (of 32) per block.
__global__ __launch_bounds__(256, 4) void gat_attn(
    const int* __restrict__ adj, const float* __restrict__ s_src,
    const float* __restrict__ s_dst, const float* __restrict__ ba_p,
    const __hip_bfloat16* __restrict__ hbT,
    float* __restrict__ num, float* __restrict__ lpart, int njt) {
    int tid = threadIdx.x;
    int w = tid >> 6, lane = tid & 63;
    int lm = lane & 15, lq = lane >> 4;
    int b = blockIdx.x;
    int ib = b & 127;          // row-block (64 rows)
    int jh = b >> 7;           // j-split index
    int i0 = ib * 64 + w * 16; // this wave's row base
    int jb0 = jh * (njt * 32);

    float ssi = s_src[i0 + lm] + ba_p[0];

    const int* arow = adj + (size_t)(i0 + lm) * NN + jb0 + lq * 8;
    const float* sd = s_dst + jb0 + lq * 8;
    const __hip_bfloat16* hbb = hbT + (size_t)lm * NN + jb0 + lq * 8;

    floatx4 acc[8] = {};
    floatx4 accd = {};
    const short8 ones = { 0x3F80, 0x3F80, 0x3F80, 0x3F80, 0x3F80, 0x3F80, 0x3F80, 0x3F80 };

    // prefetch tile 0 (adj + s_dst are the HBM-latency-critical loads)
    int4 a0 = *(const int4*)arow;
    int4 a1 = *(const int4*)(arow + 4);
    float4 d0 = *(const float4*)sd;
    float4 d1 = *(const float4*)(sd + 4);

    for (int t = 0; t < njt; t++) {
        int4 ca0 = a0, ca1 = a1;
        float4 cd0 = d0, cd1 = d1;
        if (t + 1 < njt) {
            a0 = *(const int4*)(arow + (t + 1) * 32);
            a1 = *(const int4*)(arow + (t + 1) * 32 + 4);
            d0 = *(const float4*)(sd + (t + 1) * 32);
            d1 = *(const float4*)(sd + (t + 1) * 32 + 4);
        }
        // p for this lane's 8 A-fragment elements
        float p[8];
        {
            float e;
            e = ssi + cd0.x; e = fmaxf(e, 0.01f * e); p[0] = ca0.x ? __expf(e) : 0.f;
            e = ssi + cd0.y; e = fmaxf(e, 0.01f * e); p[1] = ca0.y ? __expf(e) : 0.f;
            e = ssi + cd0.z; e = fmaxf(e, 0.01f * e); p[2] = ca0.z ? __expf(e) : 0.f;
            e = ssi + cd0.w; e = fmaxf(e, 0.01f * e); p[3] = ca0.w ? __expf(e) : 0.f;
            e = ssi + cd1.x; e = fmaxf(e, 0.01f * e); p[4] = ca1.x ? __expf(e) : 0.f;
            e = ssi + cd1.y; e = fmaxf(e, 0.01f * e); p[5] = ca1.y ? __expf(e) : 0.f;
            e = ssi + cd1.z; e = fmaxf(e, 0.01f * e); p[6] = ca1.z ? __expf(e) : 0.f;
            e = ssi + cd1.w; e = fmaxf(e, 0.01f * e); p[7] = ca1.w ? __expf(e) : 0.f;
        }
        union { short8 v; __hip_bfloat162 q[4]; } af;
        af.q[0] = __float22bfloat162_rn(make_float2(p[0], p[1]));
        af.q[1] = __float22bfloat162_rn(make_float2(p[2], p[3]));
        af.q[2] = __float22bfloat162_rn(make_float2(p[4], p[5]));
        af.q[3] = __float22bfloat162_rn(make_float2(p[6], p[7]));

        size_t off = (size_t)t * 32;
#pragma unroll
        for (int f = 0; f < 8; f++) {
            short8 bf = *(const short8*)(hbb + (size_t)f * 16 * NN + off);
            acc[f] = __builtin_amdgcn_mfma_f32_16x16x32_bf16(af.v, bf, acc[f], 0, 0, 0);
        }
        accd = __builtin_amdgcn_mfma_f32_16x16x32_bf16(af.v, ones, accd, 0, 0, 0);
    }

    // epilogue: C/D layout col=lm, row=lq*4+r
    float* nb = num + ((size_t)jh * NN + i0) * DOUT;
#pragma unroll
    for (int f = 0; f < 8; f++)
#pragma unroll
        for (int r = 0; r < 4; r++)
            nb[(size_t)(lq * 4 + r) * DOUT + f * 16 + lm] = acc[f][r];
    if (lm == 0) {
#pragma unroll
        for (int r = 0; r < 4; r++)
            lpart[(size_t)jh * NN + i0 + lq * 4 + r] = accd[r];
    }
}

// ---------------- kernel 3: combine partials, divide ----------------
__global__ void gat_combine(const float* __restrict__ num, const float* __restrict__ lpart,
                            float* __restrict__ out, int jsplit) {
    int gid = blockIdx.x * blockDim.x + threadIdx.x;  // 262144 threads, one float4 each
    int idx = gid * 4;
    int i = idx >> 7;
    float den = 0.f;
    for (int s = 0; s < jsplit; s++) den += lpart[(size_t)s * NN + i];
    float inv = 1.0f / den;
    float4 o = make_float4(0.f, 0.f, 0.f, 0.f);
    for (int s = 0; s < jsplit; s++) {
        float4 n = *(const float4*)&num[(size_t)s * NN * DOUT + idx];
        o.x += n.x; o.y += n.y; o.z += n.z; o.w += n.w;
    }
    o.x *= inv; o.y *= inv; o.z *= inv; o.w *= inv;
    *(float4*)&out[idx] = o;
}

extern "C" void kernel_launch(void* const* d_in, const int* in_sizes, int n_in,
                              void* d_out, int out_size, void* d_ws, size_t ws_size,
                              hipStream_t stream) {
    const float* x  = (const float*)d_in[0];
    const int* adj  = (const int*)d_in[1];
    const float* W  = (const float*)d_in[2];
    const float* bW = (const float*)d_in[3];
    const float* a1 = (const float*)d_in[4];
    const float* a2 = (const float*)d_in[5];
    const float* ba = (const float*)d_in[6];
    float* out = (float*)d_out;

    char* ws = (char*)d_ws;
    __hip_bfloat16* hbT = (__hip_bfloat16*)ws;                    // 2 MB   [128][8192]
    __hip_bfloat16* WT  = (__hip_bfloat16*)(ws + 2097152);        // 64 KB  [128][256]
    float* s_src        = (float*)(ws + 2162688);                 // 32 KB
    float* s_dst        = (float*)(ws + 2195456);                 // 32 KB
    float* lpart        = (float*)(ws + 2228224);                 // 256 KB [<=8][8192]
    float* num          = (float*)(ws + 2490368);                 // jsplit*4 MB [jsplit][8192][128]

    // pick the largest j-split (partial count) the workspace allows: more splits
    // = more blocks = better latency hiding in gat_attn.
    size_t base = 2490368;
    int jsplit = 2;
    if (ws_size >= base + (size_t)8 * NN * DOUT * 4) jsplit = 8;
    else if (ws_size >= base + (size_t)4 * NN * DOUT * 4) jsplit = 4;
    int njt = NN / (32 * jsplit);  // j-tiles of 32 per block

    prep_wt<<<128, 256, 0, stream>>>(W, WT);
    gat_h<<<256, 256, 0, stream>>>(x, WT, bW, a1, a2, hbT, s_src, s_dst);
    gat_attn<<<128 * jsplit, 256, 0, stream>>>(adj, s_src, s_dst, ba, hbT, num, lpart, njt);
    gat_combine<<<1024, 256, 0, stream>>>(num, lpart, out, jsplit);
}